// Round 2
// baseline (796.483 us; speedup 1.0000x reference)
//
#include <hip/hip_runtime.h>

// Problem constants (from reference): B=2, S=2048, IN=4096, OUT=4096, RANK=8, LORA_R=16
#define M_DIM 4096   // B*S
#define IN_DIM 4096
#define OUT_DIM 4096
#define RANK 8
#define LORA_R 16
#define LORA_SCALING 1.0f   // 16.0 / LORA_R

typedef __bf16 bf16;
typedef bf16  bf16x4 __attribute__((ext_vector_type(4)));
typedef bf16  bf16x8 __attribute__((ext_vector_type(8)));
typedef float f32x4  __attribute__((ext_vector_type(4)));

// -------------------------------------------------------------------------
// Kernel 1: fold rank-8 scale factor + rank-16 LoRA into one bf16 weight.
// W_tot[o,i] = weight[o,i] * sum_k(scale_A[o,k]*g[k]*scale_B[k,i])
//            + sum_r(lora_B[o,r]*lora_A[r,i])
//
// R1 post-mortem fix: v1 held sb[8]+la[16] (96 VGPRs of panel cache) live
// across the row loop -> 256 VGPR + scratch spill (778 MB HBM, 390 us).
// v2 streams panels through acc[8] only: acc (32 VGPR) + one 4-wide chunk
// in flight. scale_B/lora_A chunks are re-read per block but are L2-resident
// (384 KB total panels, 512 blocks -> ~190 MB from L2 at 34 TB/s ~ 6 us).
// -------------------------------------------------------------------------
#define OG 8
__global__ __launch_bounds__(256) void prep_weight(
    const float* __restrict__ weight, const float* __restrict__ scale_A,
    const float* __restrict__ scale_B, const float* __restrict__ g,
    const float* __restrict__ lora_A, const float* __restrict__ lora_B,
    bf16* __restrict__ wt)
{
    __shared__ float s_sa[OG][RANK];     // scale_A * g, per block-row
    __shared__ float s_lb[OG][LORA_R];   // lora_B * LORA_SCALING
    const int o0 = blockIdx.x * OG;
    const int t  = threadIdx.x;
    if (t < OG * RANK) {
        int r8 = t / RANK, k = t % RANK;
        s_sa[r8][k] = scale_A[(o0 + r8) * RANK + k] * g[k];
    }
    if (t < OG * LORA_R) {
        int r8 = t / LORA_R, r = t % LORA_R;
        s_lb[r8][r] = lora_B[(o0 + r8) * LORA_R + r] * LORA_SCALING;
    }
    __syncthreads();

    for (int i0 = t * 4; i0 < IN_DIM; i0 += 256 * 4) {
        f32x4 acc[OG];
#pragma unroll
        for (int r8 = 0; r8 < OG; ++r8) acc[r8] = {0.f, 0.f, 0.f, 0.f};

        // Pass 1: acc[r8] = sum_k (scale_A[o,k]*g[k]) * scale_B[k, chunk]
#pragma unroll
        for (int k = 0; k < RANK; ++k) {
            f32x4 sbk = *(const f32x4*)(scale_B + k * IN_DIM + i0);
#pragma unroll
            for (int r8 = 0; r8 < OG; ++r8) acc[r8] += s_sa[r8][k] * sbk;
        }
        // Pass 2: acc[r8] *= weight[o, chunk]
#pragma unroll
        for (int r8 = 0; r8 < OG; ++r8) {
            f32x4 wv = *(const f32x4*)(weight + (size_t)(o0 + r8) * IN_DIM + i0);
            acc[r8] *= wv;
        }
        // Pass 3: acc[r8] += sum_r (lora_B[o,r]*scaling) * lora_A[r, chunk]
#pragma unroll
        for (int r = 0; r < LORA_R; ++r) {
            f32x4 lak = *(const f32x4*)(lora_A + r * IN_DIM + i0);
#pragma unroll
            for (int r8 = 0; r8 < OG; ++r8) acc[r8] += s_lb[r8][r] * lak;
        }
        // Store bf16
#pragma unroll
        for (int r8 = 0; r8 < OG; ++r8) {
            bf16x4 h = { (bf16)acc[r8][0], (bf16)acc[r8][1],
                         (bf16)acc[r8][2], (bf16)acc[r8][3] };
            *(bf16x4*)(wt + (size_t)(o0 + r8) * IN_DIM + i0) = h;
        }
    }
}

// -------------------------------------------------------------------------
// Kernel 2: cast x (fp32) -> bf16, vectorized float4 -> bf16x4.
// -------------------------------------------------------------------------
__global__ __launch_bounds__(256) void cast_x(
    const float* __restrict__ x, bf16* __restrict__ xb, int n4)
{
    int idx    = blockIdx.x * blockDim.x + threadIdx.x;
    int stride = gridDim.x * blockDim.x;
    for (int i = idx; i < n4; i += stride) {
        f32x4 v = *(const f32x4*)(x + (size_t)i * 4);
        bf16x4 h = { (bf16)v[0], (bf16)v[1], (bf16)v[2], (bf16)v[3] };
        *(bf16x4*)(xb + (size_t)i * 4) = h;
    }
}

// -------------------------------------------------------------------------
// Kernel 3: bf16 GEMM, C[m,n] = sum_k A[m,k] * Bw[n,k]  (B^T layout).
// m97 structure: 128x128 tile, BK=32, 4 waves (2x2), each wave 4x4 tiles of
// mfma_f32_16x16x32_bf16; staging via global_load_lds width=16 (direct-to-LDS
// DMA, wave-uniform base + lane*16 => LDS must be unpadded/linear in tid).
// -------------------------------------------------------------------------
#define BM 128
#define BN 128
#define BK 32

__device__ __forceinline__ void gload_lds16(const bf16* g, bf16* l) {
    __builtin_amdgcn_global_load_lds(
        (const __attribute__((address_space(1))) void*)g,
        (__attribute__((address_space(3))) void*)l,
        16, 0, 0);
}

__global__ __launch_bounds__(256) void gemm_bt(
    const bf16* __restrict__ A,   // [M_DIM, IN_DIM] row-major bf16
    const bf16* __restrict__ Bw,  // [OUT_DIM, IN_DIM] row-major bf16
    float* __restrict__ C)        // [M_DIM, OUT_DIM] row-major fp32
{
    __shared__ __align__(16) bf16 sA[BM * BK];  // [128][32], row stride 64 B
    __shared__ __align__(16) bf16 sB[BN * BK];

    const int t    = threadIdx.x;
    const int w    = t >> 6;     // wave id 0..3
    const int lane = t & 63;
    const int m0   = blockIdx.x * BM;
    const int n0   = blockIdx.y * BN;
    const int wm   = (w >> 1) * 64;  // wave row offset in tile
    const int wn   = (w & 1) * 64;   // wave col offset in tile

    // Staging: thread t's 16 B lands at LDS byte t*16 (wave base + lane*16).
    // Byte t*16 => tile row t/4, col-bytes (t&3)*16 => bf16 col (t&3)*8.
    const int srow = t >> 2;        // 0..63 (issue 0), +64 for issue 1
    const int scol = (t & 3) * 8;   // bf16 col within BK
    const bf16* gA0 = A  + (size_t)(m0 + srow)      * IN_DIM + scol;
    const bf16* gA1 = A  + (size_t)(m0 + 64 + srow) * IN_DIM + scol;
    const bf16* gB0 = Bw + (size_t)(n0 + srow)      * IN_DIM + scol;
    const bf16* gB1 = Bw + (size_t)(n0 + 64 + srow) * IN_DIM + scol;
    bf16* lA0 = &sA[w * 512];          // wave-uniform LDS bases (bf16 elems)
    bf16* lA1 = &sA[2048 + w * 512];
    bf16* lB0 = &sB[w * 512];
    bf16* lB1 = &sB[2048 + w * 512];

    f32x4 acc[4][4] = {};

    const int lm = lane & 15;   // A: m, B: n within 16
    const int lq = lane >> 4;   // k-quad: k = lq*8 + j

    for (int k0 = 0; k0 < IN_DIM; k0 += BK) {
        __syncthreads();  // previous iter's ds_reads done before overwrite
        gload_lds16(gA0 + k0, lA0);
        gload_lds16(gA1 + k0, lA1);
        gload_lds16(gB0 + k0, lB0);
        gload_lds16(gB1 + k0, lB1);
        __syncthreads();  // drains vmcnt: staged tiles visible

        bf16x8 af[4], bfr[4];
#pragma unroll
        for (int tm = 0; tm < 4; ++tm)
            af[tm] = *(const bf16x8*)&sA[(wm + tm * 16 + lm) * BK + lq * 8];
#pragma unroll
        for (int tn = 0; tn < 4; ++tn)
            bfr[tn] = *(const bf16x8*)&sB[(wn + tn * 16 + lm) * BK + lq * 8];
#pragma unroll
        for (int tm = 0; tm < 4; ++tm)
#pragma unroll
            for (int tn = 0; tn < 4; ++tn)
                acc[tm][tn] = __builtin_amdgcn_mfma_f32_16x16x32_bf16(
                    af[tm], bfr[tn], acc[tm][tn], 0, 0, 0);
    }

    // Epilogue. C/D layout (m89/m91-verified): col = lane&15, row = (lane>>4)*4 + reg.
    const int ccol = lane & 15;
    const int crow = (lane >> 4) * 4;
#pragma unroll
    for (int tm = 0; tm < 4; ++tm)
#pragma unroll
        for (int tn = 0; tn < 4; ++tn) {
            float* cp = C + (size_t)(m0 + wm + tm * 16 + crow) * OUT_DIM
                          + (n0 + wn + tn * 16 + ccol);
#pragma unroll
            for (int j = 0; j < 4; ++j)
                cp[(size_t)j * OUT_DIM] = acc[tm][tn][j];
        }
}

// -------------------------------------------------------------------------
extern "C" void kernel_launch(void* const* d_in, const int* in_sizes, int n_in,
                              void* d_out, int out_size, void* d_ws, size_t ws_size,
                              hipStream_t stream) {
    (void)in_sizes; (void)n_in; (void)out_size; (void)ws_size;
    const float* x        = (const float*)d_in[0];
    const float* weight   = (const float*)d_in[1];
    const float* scale_A  = (const float*)d_in[2];
    const float* scale_B  = (const float*)d_in[3];
    const float* g        = (const float*)d_in[4];
    const float* lora_A   = (const float*)d_in[5];
    const float* lora_B   = (const float*)d_in[6];
    float* out = (float*)d_out;

    bf16* xb = (bf16*)d_ws;                                             // 32 MiB
    bf16* wt = (bf16*)((char*)d_ws + (size_t)M_DIM * IN_DIM * sizeof(bf16));  // 32 MiB

    prep_weight<<<OUT_DIM / OG, 256, 0, stream>>>(weight, scale_A, scale_B, g,
                                                  lora_A, lora_B, wt);
    cast_x<<<2048, 256, 0, stream>>>(x, xb, (M_DIM * IN_DIM) / 4);

    dim3 grid(M_DIM / BM, OUT_DIM / BN);  // 32 x 32 = 1024 blocks, 4/CU
    gemm_bt<<<grid, 256, 0, stream>>>(xb, wt, out);
}

// Round 3
// 375.796 us; speedup vs baseline: 2.1195x; 2.1195x over previous
//
#include <hip/hip_runtime.h>

// Problem constants (from reference): B=2, S=2048, IN=4096, OUT=4096, RANK=8, LORA_R=16
#define M_DIM 4096   // B*S
#define IN_DIM 4096
#define OUT_DIM 4096
#define RANK 8
#define LORA_R 16
#define LORA_SCALING 1.0f   // 16.0 / LORA_R

typedef __bf16 bf16;
typedef bf16  bf16x4 __attribute__((ext_vector_type(4)));
typedef bf16  bf16x8 __attribute__((ext_vector_type(8)));
typedef float f32x4  __attribute__((ext_vector_type(4)));

// -------------------------------------------------------------------------
// Kernel 1: fold rank-8 scale factor + rank-16 LoRA into one bf16 weight.
// W_tot[o,i] = weight[o,i] * sum_k(scale_A[o,k]*g[k]*scale_B[k,i])
//            + sum_r(lora_B[o,r]*lora_A[r,i])
//
// R1: panel cache in regs -> 256 VGPR spill (778 MB HBM).
// R2: streaming acc rewrite STILL 256 VGPR -- the outer grid-stride loop had
//     compile-time trip count 4; the unroller interleaved 4 iterations
//     (4x acc[8] = 128 VGPR + hoisted loads) and re-created the spill.
// R3: no loop at all. 2D grid: block = (o-group of 8) x (i-chunk of 1024),
//     thread = one 4-wide chunk. Live set = acc[8] (32 VGPR) + 1 load.
// -------------------------------------------------------------------------
#define OG 8
__global__ __launch_bounds__(256) void prep_weight(
    const float* __restrict__ weight, const float* __restrict__ scale_A,
    const float* __restrict__ scale_B, const float* __restrict__ g,
    const float* __restrict__ lora_A, const float* __restrict__ lora_B,
    bf16* __restrict__ wt)
{
    __shared__ float s_sa[OG][RANK];     // scale_A * g, per block-row
    __shared__ float s_lb[OG][LORA_R];   // lora_B * LORA_SCALING
    const int o0 = blockIdx.x * OG;
    const int t  = threadIdx.x;
    if (t < OG * RANK) {
        int r8 = t / RANK, k = t % RANK;
        s_sa[r8][k] = scale_A[(o0 + r8) * RANK + k] * g[k];
    }
    if (t < OG * LORA_R) {
        int r8 = t / LORA_R, r = t % LORA_R;
        s_lb[r8][r] = lora_B[(o0 + r8) * LORA_R + r] * LORA_SCALING;
    }
    __syncthreads();

    const int i0 = (blockIdx.y * 256 + t) * 4;   // one chunk per thread, no loop

    f32x4 acc[OG];
#pragma unroll
    for (int r8 = 0; r8 < OG; ++r8) acc[r8] = {0.f, 0.f, 0.f, 0.f};

    // Pass 1: acc[r8] = sum_k (scale_A[o,k]*g[k]) * scale_B[k, chunk]
#pragma unroll
    for (int k = 0; k < RANK; ++k) {
        f32x4 sbk = *(const f32x4*)(scale_B + k * IN_DIM + i0);
#pragma unroll
        for (int r8 = 0; r8 < OG; ++r8) acc[r8] += s_sa[r8][k] * sbk;
    }
    // Pass 2: acc[r8] *= weight[o, chunk]
#pragma unroll
    for (int r8 = 0; r8 < OG; ++r8) {
        f32x4 wv = *(const f32x4*)(weight + (size_t)(o0 + r8) * IN_DIM + i0);
        acc[r8] *= wv;
    }
    // Pass 3: acc[r8] += sum_r (lora_B[o,r]*scaling) * lora_A[r, chunk]
#pragma unroll
    for (int r = 0; r < LORA_R; ++r) {
        f32x4 lak = *(const f32x4*)(lora_A + r * IN_DIM + i0);
#pragma unroll
        for (int r8 = 0; r8 < OG; ++r8) acc[r8] += s_lb[r8][r] * lak;
    }
    // Store bf16
#pragma unroll
    for (int r8 = 0; r8 < OG; ++r8) {
        bf16x4 h = { (bf16)acc[r8][0], (bf16)acc[r8][1],
                     (bf16)acc[r8][2], (bf16)acc[r8][3] };
        *(bf16x4*)(wt + (size_t)(o0 + r8) * IN_DIM + i0) = h;
    }
}

// -------------------------------------------------------------------------
// Kernel 2: cast x (fp32) -> bf16, vectorized float4 -> bf16x4.
// -------------------------------------------------------------------------
__global__ __launch_bounds__(256) void cast_x(
    const float* __restrict__ x, bf16* __restrict__ xb, int n4)
{
    int idx    = blockIdx.x * blockDim.x + threadIdx.x;
    int stride = gridDim.x * blockDim.x;
    for (int i = idx; i < n4; i += stride) {
        f32x4 v = *(const f32x4*)(x + (size_t)i * 4);
        bf16x4 h = { (bf16)v[0], (bf16)v[1], (bf16)v[2], (bf16)v[3] };
        *(bf16x4*)(xb + (size_t)i * 4) = h;
    }
}

// -------------------------------------------------------------------------
// Kernel 3: bf16 GEMM, C[m,n] = sum_k A[m,k] * Bw[n,k]  (B^T layout).
// m97 structure: 128x128 tile, BK=32, 4 waves (2x2), each wave 4x4 tiles of
// mfma_f32_16x16x32_bf16; staging via global_load_lds width=16 (direct-to-LDS
// DMA, wave-uniform base + lane*16 => LDS must be unpadded/linear in tid).
// -------------------------------------------------------------------------
#define BM 128
#define BN 128
#define BK 32

__device__ __forceinline__ void gload_lds16(const bf16* g, bf16* l) {
    __builtin_amdgcn_global_load_lds(
        (const __attribute__((address_space(1))) void*)g,
        (__attribute__((address_space(3))) void*)l,
        16, 0, 0);
}

__global__ __launch_bounds__(256) void gemm_bt(
    const bf16* __restrict__ A,   // [M_DIM, IN_DIM] row-major bf16
    const bf16* __restrict__ Bw,  // [OUT_DIM, IN_DIM] row-major bf16
    float* __restrict__ C)        // [M_DIM, OUT_DIM] row-major fp32
{
    __shared__ __align__(16) bf16 sA[BM * BK];  // [128][32], row stride 64 B
    __shared__ __align__(16) bf16 sB[BN * BK];

    const int t    = threadIdx.x;
    const int w    = t >> 6;     // wave id 0..3
    const int lane = t & 63;
    const int m0   = blockIdx.x * BM;
    const int n0   = blockIdx.y * BN;
    const int wm   = (w >> 1) * 64;  // wave row offset in tile
    const int wn   = (w & 1) * 64;   // wave col offset in tile

    // Staging: thread t's 16 B lands at LDS byte t*16 (wave base + lane*16).
    // Byte t*16 => tile row t/4, col-bytes (t&3)*16 => bf16 col (t&3)*8.
    const int srow = t >> 2;        // 0..63 (issue 0), +64 for issue 1
    const int scol = (t & 3) * 8;   // bf16 col within BK
    const bf16* gA0 = A  + (size_t)(m0 + srow)      * IN_DIM + scol;
    const bf16* gA1 = A  + (size_t)(m0 + 64 + srow) * IN_DIM + scol;
    const bf16* gB0 = Bw + (size_t)(n0 + srow)      * IN_DIM + scol;
    const bf16* gB1 = Bw + (size_t)(n0 + 64 + srow) * IN_DIM + scol;
    bf16* lA0 = &sA[w * 512];          // wave-uniform LDS bases (bf16 elems)
    bf16* lA1 = &sA[2048 + w * 512];
    bf16* lB0 = &sB[w * 512];
    bf16* lB1 = &sB[2048 + w * 512];

    f32x4 acc[4][4] = {};

    const int lm = lane & 15;   // A: m, B: n within 16
    const int lq = lane >> 4;   // k-quad: k = lq*8 + j

    for (int k0 = 0; k0 < IN_DIM; k0 += BK) {
        __syncthreads();  // previous iter's ds_reads done before overwrite
        gload_lds16(gA0 + k0, lA0);
        gload_lds16(gA1 + k0, lA1);
        gload_lds16(gB0 + k0, lB0);
        gload_lds16(gB1 + k0, lB1);
        __syncthreads();  // drains vmcnt: staged tiles visible

        bf16x8 af[4], bfr[4];
#pragma unroll
        for (int tm = 0; tm < 4; ++tm)
            af[tm] = *(const bf16x8*)&sA[(wm + tm * 16 + lm) * BK + lq * 8];
#pragma unroll
        for (int tn = 0; tn < 4; ++tn)
            bfr[tn] = *(const bf16x8*)&sB[(wn + tn * 16 + lm) * BK + lq * 8];
#pragma unroll
        for (int tm = 0; tm < 4; ++tm)
#pragma unroll
            for (int tn = 0; tn < 4; ++tn)
                acc[tm][tn] = __builtin_amdgcn_mfma_f32_16x16x32_bf16(
                    af[tm], bfr[tn], acc[tm][tn], 0, 0, 0);
    }

    // Epilogue. C/D layout (m89/m91-verified): col = lane&15, row = (lane>>4)*4 + reg.
    const int ccol = lane & 15;
    const int crow = (lane >> 4) * 4;
#pragma unroll
    for (int tm = 0; tm < 4; ++tm)
#pragma unroll
        for (int tn = 0; tn < 4; ++tn) {
            float* cp = C + (size_t)(m0 + wm + tm * 16 + crow) * OUT_DIM
                          + (n0 + wn + tn * 16 + ccol);
#pragma unroll
            for (int j = 0; j < 4; ++j)
                cp[(size_t)j * OUT_DIM] = acc[tm][tn][j];
        }
}

// -------------------------------------------------------------------------
extern "C" void kernel_launch(void* const* d_in, const int* in_sizes, int n_in,
                              void* d_out, int out_size, void* d_ws, size_t ws_size,
                              hipStream_t stream) {
    (void)in_sizes; (void)n_in; (void)out_size; (void)ws_size;
    const float* x        = (const float*)d_in[0];
    const float* weight   = (const float*)d_in[1];
    const float* scale_A  = (const float*)d_in[2];
    const float* scale_B  = (const float*)d_in[3];
    const float* g        = (const float*)d_in[4];
    const float* lora_A   = (const float*)d_in[5];
    const float* lora_B   = (const float*)d_in[6];
    float* out = (float*)d_out;

    bf16* xb = (bf16*)d_ws;                                             // 32 MiB
    bf16* wt = (bf16*)((char*)d_ws + (size_t)M_DIM * IN_DIM * sizeof(bf16));  // 32 MiB

    dim3 pgrid(OUT_DIM / OG, IN_DIM / (256 * 4));   // 512 x 4 blocks, no per-thread loop
    prep_weight<<<pgrid, 256, 0, stream>>>(weight, scale_A, scale_B, g,
                                           lora_A, lora_B, wt);
    cast_x<<<2048, 256, 0, stream>>>(x, xb, (M_DIM * IN_DIM) / 4);

    dim3 grid(M_DIM / BM, OUT_DIM / BN);  // 32 x 32 = 1024 blocks, 4/CU
    gemm_bt<<<grid, 256, 0, stream>>>(xb, wt, out);
}

// Round 4
// 360.382 us; speedup vs baseline: 2.2101x; 1.0428x over previous
//
#include <hip/hip_runtime.h>

// Problem constants: B=2, S=2048, IN=4096, OUT=4096, RANK=8, LORA_R=16
#define M_DIM 4096
#define IN_DIM 4096
#define OUT_DIM 4096
#define RANK 8
#define LORA_R 16
#define LORA_SCALING 1.0f

typedef __bf16 bf16;
typedef bf16  bf16x4 __attribute__((ext_vector_type(4)));
typedef bf16  bf16x8 __attribute__((ext_vector_type(8)));
typedef float f32x4  __attribute__((ext_vector_type(4)));
typedef float f32x16 __attribute__((ext_vector_type(16)));

// -------------------------------------------------------------------------
// Kernel 1: fold rank-8 scale + rank-16 LoRA into one bf16 weight.
// R3 structure (no loop, 2D grid) fixed the R1/R2 VGPR spill. Unchanged.
// -------------------------------------------------------------------------
#define OG 8
__global__ __launch_bounds__(256) void prep_weight(
    const float* __restrict__ weight, const float* __restrict__ scale_A,
    const float* __restrict__ scale_B, const float* __restrict__ g,
    const float* __restrict__ lora_A, const float* __restrict__ lora_B,
    bf16* __restrict__ wt)
{
    __shared__ float s_sa[OG][RANK];
    __shared__ float s_lb[OG][LORA_R];
    const int o0 = blockIdx.x * OG;
    const int t  = threadIdx.x;
    if (t < OG * RANK) {
        int r8 = t / RANK, k = t % RANK;
        s_sa[r8][k] = scale_A[(o0 + r8) * RANK + k] * g[k];
    }
    if (t < OG * LORA_R) {
        int r8 = t / LORA_R, r = t % LORA_R;
        s_lb[r8][r] = lora_B[(o0 + r8) * LORA_R + r] * LORA_SCALING;
    }
    __syncthreads();

    const int i0 = (blockIdx.y * 256 + t) * 4;

    f32x4 acc[OG];
#pragma unroll
    for (int r8 = 0; r8 < OG; ++r8) acc[r8] = {0.f, 0.f, 0.f, 0.f};
#pragma unroll
    for (int k = 0; k < RANK; ++k) {
        f32x4 sbk = *(const f32x4*)(scale_B + k * IN_DIM + i0);
#pragma unroll
        for (int r8 = 0; r8 < OG; ++r8) acc[r8] += s_sa[r8][k] * sbk;
    }
#pragma unroll
    for (int r8 = 0; r8 < OG; ++r8) {
        f32x4 wv = *(const f32x4*)(weight + (size_t)(o0 + r8) * IN_DIM + i0);
        acc[r8] *= wv;
    }
#pragma unroll
    for (int r = 0; r < LORA_R; ++r) {
        f32x4 lak = *(const f32x4*)(lora_A + r * IN_DIM + i0);
#pragma unroll
        for (int r8 = 0; r8 < OG; ++r8) acc[r8] += s_lb[r8][r] * lak;
    }
#pragma unroll
    for (int r8 = 0; r8 < OG; ++r8) {
        bf16x4 h = { (bf16)acc[r8][0], (bf16)acc[r8][1],
                     (bf16)acc[r8][2], (bf16)acc[r8][3] };
        *(bf16x4*)(wt + (size_t)(o0 + r8) * IN_DIM + i0) = h;
    }
}

// -------------------------------------------------------------------------
// Kernel 2: cast x fp32 -> bf16.
// -------------------------------------------------------------------------
__global__ __launch_bounds__(256) void cast_x(
    const float* __restrict__ x, bf16* __restrict__ xb, int n4)
{
    int idx    = blockIdx.x * blockDim.x + threadIdx.x;
    int stride = gridDim.x * blockDim.x;
    for (int i = idx; i < n4; i += stride) {
        f32x4 v = *(const f32x4*)(x + (size_t)i * 4);
        bf16x4 h = { (bf16)v[0], (bf16)v[1], (bf16)v[2], (bf16)v[3] };
        *(bf16x4*)(xb + (size_t)i * 4) = h;
    }
}

// -------------------------------------------------------------------------
// Kernel 3: bf16 GEMM C[m,n] = sum_k A[m,k]*Bw[n,k], R4 rewrite:
//  - mfma_f32_32x32x16_bf16 (2x2 32x32 tiles/wave): 8 MFMA x 8.07cyc/iter vs
//    16 x 4.85 for 16x16 -> 17% less matrix-pipe time (m119: 2495 vs 2075 TF).
//  - XOR chunk swizzle: chunk(row,cb) at slot row*4 + (cb ^ (row&3)).
//    Implemented on the FETCH side (global_load_lds forces slot=lane*16, so
//    lane fetches the chunk that belongs in its slot). Frag reads then start
//    at all 8 bank-quads (was 2 -> 4 extra cyc per ds_read_b128, 1.68e7
//    conflicts in R3). Frag addresses are loop-invariant.
//  - Epilogue: per-wave stride-33 LDS transpose -> 128B-contiguous dwordx4
//    C stores (R3 scalar 4B stores caused ~100 MB RFO fetch).
//  - XCD swizzle: XCD x = bid&7 owns M-band [4x,4x+4) x all N: A-footprint
//    4 MB = L2-resident, co-XCD neighbors share B-slices.
// -------------------------------------------------------------------------
#define BM 128
#define BN 128
#define BK 32

__device__ __forceinline__ void gload_lds16(const bf16* g, bf16* l) {
    __builtin_amdgcn_global_load_lds(
        (const __attribute__((address_space(1))) void*)g,
        (__attribute__((address_space(3))) void*)l,
        16, 0, 0);
}

__global__ __launch_bounds__(256) void gemm_bt(
    const bf16* __restrict__ A,   // [4096,4096] bf16 row-major
    const bf16* __restrict__ Bw,  // [4096,4096] bf16 row-major (B^T input)
    float* __restrict__ C)        // [4096,4096] fp32 row-major
{
    // smem: staging sA(8192 B) + sB(8192 B); epilogue aliases the whole
    // region as 4 waves x 32x33 f32 (16896 B total).
    __shared__ __align__(16) char smem[16896];
    bf16* sA = (bf16*)smem;
    bf16* sB = (bf16*)(smem + 8192);

    const int t    = threadIdx.x;
    const int w    = t >> 6;
    const int lane = t & 63;
    const int lh   = lane >> 5;   // k-half selector
    const int ln   = lane & 31;   // m (A) / n (B) within 32

    // XCD-compact block swizzle (1D grid, 1024 blocks)
    const int bid = blockIdx.x;
    const int xcd = bid & 7;
    const int rr_ = bid >> 3;
    const int m0  = (xcd * 4 + (rr_ & 3)) * BM;
    const int n0  = (rr_ >> 2) * BN;

    const int wm = (w >> 1) * 64;
    const int wn = (w & 1) * 64;

    // Staging: thread t -> LDS slot t (16 B). slot = row*4 + (cb ^ (row&3))
    // => row = t>>2, fetched chunk cb = (t&3) ^ (row&3).
    const int srow = t >> 2;
    const int scol = ((t & 3) ^ (srow & 3)) * 8;   // bf16 elems within BK
    const bf16* gA0 = A  + (size_t)(m0 + srow)      * IN_DIM + scol;
    const bf16* gA1 = A  + (size_t)(m0 + 64 + srow) * IN_DIM + scol;
    const bf16* gB0 = Bw + (size_t)(n0 + srow)      * IN_DIM + scol;
    const bf16* gB1 = Bw + (size_t)(n0 + 64 + srow) * IN_DIM + scol;
    bf16* lA0 = sA + w * 512;          // wave-uniform LDS bases
    bf16* lA1 = sA + 2048 + w * 512;
    bf16* lB0 = sB + w * 512;
    bf16* lB1 = sB + 2048 + w * 512;

    // Loop-invariant fragment addresses.
    // A-frag (32x32x16): m = ln, k = lh*8 + j; kstep s adds 16.
    // chunk cb = s*2 + lh, elem addr = row*32 + (cb ^ (row&3))*8.
    const bf16* pA[2][2];
    const bf16* pB[2][2];
#pragma unroll
    for (int tm = 0; tm < 2; ++tm) {
        int rowA = wm + tm * 32 + ln;
        int rowB = wn + tm * 32 + ln;
#pragma unroll
        for (int s = 0; s < 2; ++s) {
            pA[tm][s] = sA + rowA * 32 + (((s * 2 + lh) ^ (rowA & 3)) * 8);
            pB[tm][s] = sB + rowB * 32 + (((s * 2 + lh) ^ (rowB & 3)) * 8);
        }
    }

    f32x16 acc[2][2] = {};

    for (int k0 = 0; k0 < IN_DIM; k0 += BK) {
        __syncthreads();
        gload_lds16(gA0 + k0, lA0);
        gload_lds16(gA1 + k0, lA1);
        gload_lds16(gB0 + k0, lB0);
        gload_lds16(gB1 + k0, lB1);
        __syncthreads();

        bf16x8 af[2][2], bf_[2][2];
#pragma unroll
        for (int tm = 0; tm < 2; ++tm)
#pragma unroll
            for (int s = 0; s < 2; ++s) {
                af[tm][s]  = *(const bf16x8*)pA[tm][s];
                bf_[tm][s] = *(const bf16x8*)pB[tm][s];
            }
#pragma unroll
        for (int s = 0; s < 2; ++s)
#pragma unroll
            for (int tm = 0; tm < 2; ++tm)
#pragma unroll
                for (int tn = 0; tn < 2; ++tn)
                    acc[tm][tn] = __builtin_amdgcn_mfma_f32_32x32x16_bf16(
                        af[tm][s], bf_[tn][s], acc[tm][tn], 0, 0, 0);
    }

    // Epilogue: LDS transpose (stride 33) -> vectorized coalesced stores.
    __syncthreads();  // all waves' final frag reads done before smem reuse
    float* sEw = (float*)smem + w * (32 * 33);
#pragma unroll
    for (int tm = 0; tm < 2; ++tm)
#pragma unroll
        for (int tn = 0; tn < 2; ++tn) {
            // C/D layout (m74/m101): col = ln, row = (j&3) + 8*(j>>2) + 4*lh
#pragma unroll
            for (int j = 0; j < 16; ++j) {
                int row = (j & 3) + 8 * (j >> 2) + 4 * lh;
                sEw[row * 33 + ln] = acc[tm][tn][j];
            }
            // read back: lane covers row p*8 + (lane>>3), 4 consecutive cols
#pragma unroll
            for (int p = 0; p < 4; ++p) {
                int r4 = p * 8 + (lane >> 3);
                int c4 = (lane & 7) * 4;
                f32x4 v = { sEw[r4 * 33 + c4],     sEw[r4 * 33 + c4 + 1],
                            sEw[r4 * 33 + c4 + 2], sEw[r4 * 33 + c4 + 3] };
                *(f32x4*)(C + (size_t)(m0 + wm + tm * 32 + r4) * OUT_DIM
                            + (n0 + wn + tn * 32 + c4)) = v;
            }
        }
}

// -------------------------------------------------------------------------
extern "C" void kernel_launch(void* const* d_in, const int* in_sizes, int n_in,
                              void* d_out, int out_size, void* d_ws, size_t ws_size,
                              hipStream_t stream) {
    (void)in_sizes; (void)n_in; (void)out_size; (void)ws_size;
    const float* x        = (const float*)d_in[0];
    const float* weight   = (const float*)d_in[1];
    const float* scale_A  = (const float*)d_in[2];
    const float* scale_B  = (const float*)d_in[3];
    const float* g        = (const float*)d_in[4];
    const float* lora_A   = (const float*)d_in[5];
    const float* lora_B   = (const float*)d_in[6];
    float* out = (float*)d_out;

    bf16* xb = (bf16*)d_ws;
    bf16* wt = (bf16*)((char*)d_ws + (size_t)M_DIM * IN_DIM * sizeof(bf16));

    dim3 pgrid(OUT_DIM / OG, IN_DIM / (256 * 4));
    prep_weight<<<pgrid, 256, 0, stream>>>(weight, scale_A, scale_B, g,
                                           lora_A, lora_B, wt);
    cast_x<<<2048, 256, 0, stream>>>(x, xb, (M_DIM * IN_DIM) / 4);

    gemm_bt<<<(M_DIM / BM) * (OUT_DIM / BN), 256, 0, stream>>>(xb, wt, out);
}

// Round 5
// 338.117 us; speedup vs baseline: 2.3556x; 1.0658x over previous
//
#include <hip/hip_runtime.h>

// Problem constants: B=2, S=2048, IN=4096, OUT=4096, RANK=8, LORA_R=16
#define M_DIM 4096
#define IN_DIM 4096
#define OUT_DIM 4096
#define RANK 8
#define LORA_R 16
#define LORA_SCALING 1.0f

typedef __bf16 bf16;
typedef bf16  bf16x4 __attribute__((ext_vector_type(4)));
typedef bf16  bf16x8 __attribute__((ext_vector_type(8)));
typedef float f32x4  __attribute__((ext_vector_type(4)));
typedef float f32x16 __attribute__((ext_vector_type(16)));

// -------------------------------------------------------------------------
// Kernel 1 (fused): blocks [0,2048) fold weight; blocks [2048,4096) cast x.
// Both memory-bound; fusing overlaps them instead of serializing on stream.
// prep: R3 structure (no per-thread loop -> no unroll-driven VGPR spill).
// -------------------------------------------------------------------------
#define OG 8
__global__ __launch_bounds__(256) void prep_fused(
    const float* __restrict__ weight, const float* __restrict__ scale_A,
    const float* __restrict__ scale_B, const float* __restrict__ g,
    const float* __restrict__ lora_A, const float* __restrict__ lora_B,
    const float* __restrict__ x, bf16* __restrict__ wt, bf16* __restrict__ xb)
{
    const int t = threadIdx.x;
    if (blockIdx.x < 2048) {
        // ---- prep_weight: block = (o-group of 8) x (i-chunk of 1024) ----
        __shared__ float s_sa[OG][RANK];
        __shared__ float s_lb[OG][LORA_R];
        const int o0 = (blockIdx.x >> 2) * OG;
        if (t < OG * RANK) {
            int r8 = t / RANK, k = t % RANK;
            s_sa[r8][k] = scale_A[(o0 + r8) * RANK + k] * g[k];
        }
        if (t < OG * LORA_R) {
            int r8 = t / LORA_R, r = t % LORA_R;
            s_lb[r8][r] = lora_B[(o0 + r8) * LORA_R + r] * LORA_SCALING;
        }
        __syncthreads();

        const int i0 = ((blockIdx.x & 3) * 256 + t) * 4;

        f32x4 acc[OG];
#pragma unroll
        for (int r8 = 0; r8 < OG; ++r8) acc[r8] = {0.f, 0.f, 0.f, 0.f};
#pragma unroll
        for (int k = 0; k < RANK; ++k) {
            f32x4 sbk = *(const f32x4*)(scale_B + k * IN_DIM + i0);
#pragma unroll
            for (int r8 = 0; r8 < OG; ++r8) acc[r8] += s_sa[r8][k] * sbk;
        }
#pragma unroll
        for (int r8 = 0; r8 < OG; ++r8) {
            f32x4 wv = *(const f32x4*)(weight + (size_t)(o0 + r8) * IN_DIM + i0);
            acc[r8] *= wv;
        }
#pragma unroll
        for (int r = 0; r < LORA_R; ++r) {
            f32x4 lak = *(const f32x4*)(lora_A + r * IN_DIM + i0);
#pragma unroll
            for (int r8 = 0; r8 < OG; ++r8) acc[r8] += s_lb[r8][r] * lak;
        }
#pragma unroll
        for (int r8 = 0; r8 < OG; ++r8) {
            bf16x4 h = { (bf16)acc[r8][0], (bf16)acc[r8][1],
                         (bf16)acc[r8][2], (bf16)acc[r8][3] };
            *(bf16x4*)(wt + (size_t)(o0 + r8) * IN_DIM + i0) = h;
        }
    } else {
        // ---- cast x fp32 -> bf16, grid-stride f32x4 ----
        const int n4  = (M_DIM * IN_DIM) / 4;
        int idx    = (blockIdx.x - 2048) * 256 + t;
        int stride = 2048 * 256;
        for (int i = idx; i < n4; i += stride) {
            f32x4 v = *(const f32x4*)(x + (size_t)i * 4);
            bf16x4 h = { (bf16)v[0], (bf16)v[1], (bf16)v[2], (bf16)v[3] };
            *(bf16x4*)(xb + (size_t)i * 4) = h;
        }
    }
}

// -------------------------------------------------------------------------
// Kernel 2: bf16 GEMM C[m,n] = sum_k A[m,k]*Bw[n,k].
// R5 change: XOR swizzle sc = cb ^ ((row>>1)&3)  [was cb ^ (row&3)].
// Bank model (validated R4: 12.3 extra cyc/read measured vs 12 predicted):
// bank = (row*16 + sc*4)%32, LDS phases = 16 lanes. Old swizzle: even lanes
// had ln&3 in {0,2} -> 2 sc values -> 4 touches/bank (4-way). New: (ln>>1)&3
// sweeps all 4 values per parity class -> start banks {0,16,4,20,8,24,12,28}
// -> every bank exactly 2x per phase = free (m136).
// Staging fetch side: slot=t*16 fixed => thread t fetches chunk
// (t&3) ^ ((t>>3)&3) of row t>>2.
// -------------------------------------------------------------------------
#define BM 128
#define BN 128
#define BK 32

__device__ __forceinline__ void gload_lds16(const bf16* g, bf16* l) {
    __builtin_amdgcn_global_load_lds(
        (const __attribute__((address_space(1))) void*)g,
        (__attribute__((address_space(3))) void*)l,
        16, 0, 0);
}

__global__ __launch_bounds__(256) void gemm_bt(
    const bf16* __restrict__ A,   // [4096,4096] bf16 row-major
    const bf16* __restrict__ Bw,  // [4096,4096] bf16 row-major (B^T input)
    float* __restrict__ C)        // [4096,4096] fp32 row-major
{
    __shared__ __align__(16) char smem[16896];
    bf16* sA = (bf16*)smem;
    bf16* sB = (bf16*)(smem + 8192);

    const int t    = threadIdx.x;
    const int w    = t >> 6;
    const int lane = t & 63;
    const int lh   = lane >> 5;   // k-half selector
    const int ln   = lane & 31;   // m (A) / n (B) within 32

    // XCD-compact block swizzle (1D grid, 1024 blocks)
    const int bid = blockIdx.x;
    const int xcd = bid & 7;
    const int rr_ = bid >> 3;
    const int m0  = (xcd * 4 + (rr_ & 3)) * BM;
    const int n0  = (rr_ >> 2) * BN;

    const int wm = (w >> 1) * 64;
    const int wn = (w & 1) * 64;

    // Staging: thread t -> LDS slot t (16 B each). Fetch the chunk that
    // belongs in this slot under sc = cb ^ ((row>>1)&3).
    const int srow = t >> 2;
    const int scol = ((t & 3) ^ ((t >> 3) & 3)) * 8;   // bf16 col within BK
    const bf16* gA0 = A  + (size_t)(m0 + srow)      * IN_DIM + scol;
    const bf16* gA1 = A  + (size_t)(m0 + 64 + srow) * IN_DIM + scol;
    const bf16* gB0 = Bw + (size_t)(n0 + srow)      * IN_DIM + scol;
    const bf16* gB1 = Bw + (size_t)(n0 + 64 + srow) * IN_DIM + scol;
    bf16* lA0 = sA + w * 512;          // wave-uniform LDS bases
    bf16* lA1 = sA + 2048 + w * 512;
    bf16* lB0 = sB + w * 512;
    bf16* lB1 = sB + 2048 + w * 512;

    // Loop-invariant fragment addresses: (row, chunk cb = s*2+lh) lives at
    // row*32 + (cb ^ ((row>>1)&3))*8.
    const bf16* pA[2][2];
    const bf16* pB[2][2];
#pragma unroll
    for (int tm = 0; tm < 2; ++tm) {
        int rowA = wm + tm * 32 + ln;
        int rowB = wn + tm * 32 + ln;
#pragma unroll
        for (int s = 0; s < 2; ++s) {
            pA[tm][s] = sA + rowA * 32 + (((s * 2 + lh) ^ ((rowA >> 1) & 3)) * 8);
            pB[tm][s] = sB + rowB * 32 + (((s * 2 + lh) ^ ((rowB >> 1) & 3)) * 8);
        }
    }

    f32x16 acc[2][2] = {};

    for (int k0 = 0; k0 < IN_DIM; k0 += BK) {
        __syncthreads();
        gload_lds16(gA0 + k0, lA0);
        gload_lds16(gA1 + k0, lA1);
        gload_lds16(gB0 + k0, lB0);
        gload_lds16(gB1 + k0, lB1);
        __syncthreads();

        bf16x8 af[2][2], bf_[2][2];
#pragma unroll
        for (int tm = 0; tm < 2; ++tm)
#pragma unroll
            for (int s = 0; s < 2; ++s) {
                af[tm][s]  = *(const bf16x8*)pA[tm][s];
                bf_[tm][s] = *(const bf16x8*)pB[tm][s];
            }
#pragma unroll
        for (int s = 0; s < 2; ++s)
#pragma unroll
            for (int tm = 0; tm < 2; ++tm)
#pragma unroll
                for (int tn = 0; tn < 2; ++tn)
                    acc[tm][tn] = __builtin_amdgcn_mfma_f32_32x32x16_bf16(
                        af[tm][s], bf_[tn][s], acc[tm][tn], 0, 0, 0);
    }

    // Epilogue: LDS transpose (stride 33) -> 128B-contiguous dwordx4 stores.
    __syncthreads();
    float* sEw = (float*)smem + w * (32 * 33);
#pragma unroll
    for (int tm = 0; tm < 2; ++tm)
#pragma unroll
        for (int tn = 0; tn < 2; ++tn) {
            // C/D layout (m74/m101): col = ln, row = (j&3) + 8*(j>>2) + 4*lh
#pragma unroll
            for (int j = 0; j < 16; ++j) {
                int row = (j & 3) + 8 * (j >> 2) + 4 * lh;
                sEw[row * 33 + ln] = acc[tm][tn][j];
            }
#pragma unroll
            for (int p = 0; p < 4; ++p) {
                int r4 = p * 8 + (lane >> 3);
                int c4 = (lane & 7) * 4;
                f32x4 v = { sEw[r4 * 33 + c4],     sEw[r4 * 33 + c4 + 1],
                            sEw[r4 * 33 + c4 + 2], sEw[r4 * 33 + c4 + 3] };
                *(f32x4*)(C + (size_t)(m0 + wm + tm * 32 + r4) * OUT_DIM
                            + (n0 + wn + tn * 32 + c4)) = v;
            }
        }
}

// -------------------------------------------------------------------------
extern "C" void kernel_launch(void* const* d_in, const int* in_sizes, int n_in,
                              void* d_out, int out_size, void* d_ws, size_t ws_size,
                              hipStream_t stream) {
    (void)in_sizes; (void)n_in; (void)out_size; (void)ws_size;
    const float* x        = (const float*)d_in[0];
    const float* weight   = (const float*)d_in[1];
    const float* scale_A  = (const float*)d_in[2];
    const float* scale_B  = (const float*)d_in[3];
    const float* g        = (const float*)d_in[4];
    const float* lora_A   = (const float*)d_in[5];
    const float* lora_B   = (const float*)d_in[6];
    float* out = (float*)d_out;

    bf16* xb = (bf16*)d_ws;
    bf16* wt = (bf16*)((char*)d_ws + (size_t)M_DIM * IN_DIM * sizeof(bf16));

    prep_fused<<<4096, 256, 0, stream>>>(weight, scale_A, scale_B, g,
                                         lora_A, lora_B, x, wt, xb);

    gemm_bt<<<(M_DIM / BM) * (OUT_DIM / BN), 256, 0, stream>>>(xb, wt, out);
}